// Round 4
// baseline (6315.839 us; speedup 1.0000x reference)
//
#include <hip/hip_runtime.h>
#include <hip/hip_cooperative_groups.h>
#include <math.h>

namespace cg = cooperative_groups;

// ---------------------------------------------------------------------------
// ConvLSTM stack: 4 x (ConvLSTM2D + MaxPool(1,2,2)) -> Flatten -> Dense -> Softmax
// Channels-last (B,T,H,W,C) everywhere (matches ref).
//
//  L1: Cin=3,  F=4,  128->126 -> pool 63   merged-gates, 512 blocks, 4 px/thr
//  L2: Cin=4,  F=8,   63-> 61 -> pool 31   merged-gates, 466 blocks, 1 px/thr
//  L3: Cin=8,  F=12,  31-> 29 -> pool 15   gate-split waves, 421 blocks
//  L4: Cin=12, F=16,  15-> 13 -> pool 7    gate-split waves,  85 blocks
//
// Round-4: ONE cooperative kernel per layer. Loop over t inside the kernel
// with grid.sync(); c stays in REGISTERS across all 24 steps; h ring is
// 2 slots (ping-pong, cache-resident); input conv recomputed per step
// (P slice is 2-6 MB, L2/L3-resident -> recompute beats the 366 MB xg
// materialization that was write-bound in round 3). Pool(t-1) runs as a
// phase overlapped with step(t): pool reads slot (t-1)&1, step writes t&1,
// and the grid.sync at iteration end separates pool(t-1) reads from
// step(t+1)'s overwrite of that slot.
// ---------------------------------------------------------------------------

static __device__ __forceinline__ float hsig(float x) {
    return fminf(fmaxf(fmaf(0.2f, x, 0.5f), 0.0f), 1.0f);
}
static __device__ __forceinline__ float ftanh(float x) {
    // tanh(x) = 1 - 2/(e^{2x}+1);  |err| ~1e-6, exact at +-inf
    float e = __builtin_amdgcn_exp2f(x * 2.88539008177792681f);
    return 1.0f - 2.0f * __builtin_amdgcn_rcpf(e + 1.0f);
}

// MaxPool(2,2) SAME phase for timestep tt: grid-stride over (B,HP,WP,F).
template<int F, int HO, int WO, int HP, int WP>
static __device__ __forceinline__
void pool_phase(const float* __restrict__ h,       // ring slot (B,HO,WO,F)
                float* __restrict__ pooled,        // (B,T,HP,WP,F)
                int tt, int gtid, int NTH)
{
    constexpr int B = 32, T = 24;
    constexpr int NP = B * HP * WP * F;
    for (int i = gtid; i < NP; i += NTH) {
        const int f  = i % F;
        const int xo = (i / F) % WP;
        const int yo = (i / (F * WP)) % HP;
        const int b  = i / (F * WP * HP);
        const int y0 = 2 * yo, x0 = 2 * xo;
        const float* base = h + (((size_t)b * HO + y0) * WO + x0) * F + f;
        float m = base[0];
        if (x0 + 1 < WO) m = fmaxf(m, base[F]);
        if (y0 + 1 < HO) {
            m = fmaxf(m, base[(size_t)WO * F]);
            if (x0 + 1 < WO) m = fmaxf(m, base[(size_t)WO * F + F]);
        }
        pooled[(((size_t)b * T + tt) * HP * WP + yo * WP + xo) * F + f] = m;
    }
}

// ---- merged-gates cooperative layer kernel (L1, L2) ----
// Thread owns PPT pixels for ALL t; computes all 4 gates (gate = uniform loop
// index -> all weight/bias loads are wave-uniform s_loads); c in registers.
template<int CIN, int F, int HIN, int WIN, int PPT>
__global__ __launch_bounds__(256, 2)
void layer_merged_k(const float* __restrict__ P,    // (B,T,HIN,WIN,CIN)
                    const float* __restrict__ Wx,   // (3,3,CIN,4F)
                    const float* __restrict__ Wh,   // (3,3,F,4F)
                    const float* __restrict__ bias, // (4F)
                    float* __restrict__ ring,       // 2 * B*HO*WO*F
                    float* __restrict__ pooled)     // (B,T,HP,WP,F)
{
    constexpr int B = 32, T = 24, HO = HIN - 2, WO = WIN - 2, G = 4 * F;
    constexpr int HP = (HO + 1) / 2, WP = (WO + 1) / 2;
    constexpr int NPIX = B * HO * WO;
    constexpr size_t RS = (size_t)NPIX * F;
    const int NTH  = gridDim.x * 256;
    const int gtid = blockIdx.x * 256 + threadIdx.x;
    cg::grid_group grid = cg::this_grid();

    float creg[PPT][F];
    #pragma unroll
    for (int k = 0; k < PPT; ++k)
        #pragma unroll
        for (int f = 0; f < F; ++f) creg[k][f] = 0.0f;

    for (int t = 0; t < T; ++t) {
        if (t > 0)
            pool_phase<F, HO, WO, HP, WP>(ring + ((t - 1) & 1) * RS, pooled,
                                          t - 1, gtid, NTH);
        const float* hprev = ring + ((t + 1) & 1) * RS;
        float*       hcur  = ring + (t & 1) * RS;

        #pragma unroll
        for (int k = 0; k < PPT; ++k) {
            const int pix = gtid + k * NTH;
            if (pix < NPIX) {
                const int s  = pix % (HO * WO);
                const int b  = pix / (HO * WO);
                const int xx = s % WO, yy = s / WO;

                float acc[4][F];
                #pragma unroll
                for (int g = 0; g < 4; ++g)
                    #pragma unroll
                    for (int f = 0; f < F; ++f)
                        acc[g][f] = bias[g * F + f];          // s_load

                // input conv (VALID), recomputed per step (P slice is cached)
                const float* Pt = P + (size_t)(b * T + t) * HIN * WIN * CIN;
                #pragma unroll
                for (int ky = 0; ky < 3; ++ky) {
                    #pragma unroll
                    for (int kx = 0; kx < 3; ++kx) {
                        const float* prow =
                            Pt + ((yy + ky) * WIN + (xx + kx)) * CIN;
                        float pv[CIN];
                        if constexpr (CIN % 4 == 0) {
                            #pragma unroll
                            for (int j = 0; j < CIN / 4; ++j) {
                                float4 v4 = reinterpret_cast<const float4*>(prow)[j];
                                pv[4*j] = v4.x; pv[4*j+1] = v4.y;
                                pv[4*j+2] = v4.z; pv[4*j+3] = v4.w;
                            }
                        } else {
                            #pragma unroll
                            for (int ci = 0; ci < CIN; ++ci) pv[ci] = prow[ci];
                        }
                        #pragma unroll
                        for (int ci = 0; ci < CIN; ++ci) {
                            const float v = pv[ci];
                            const float* wr =
                                Wx + (size_t)((ky * 3 + kx) * CIN + ci) * G;
                            #pragma unroll
                            for (int g = 0; g < 4; ++g)
                                #pragma unroll
                                for (int f = 0; f < F; ++f)
                                    acc[g][f] = fmaf(v, wr[g * F + f], acc[g][f]);
                        }
                    }
                }

                // recurrent conv (SAME) on h_{t-1}
                if (t > 0) {
                    const float* Hp = hprev + (size_t)b * HO * WO * F;
                    #pragma unroll
                    for (int ky = 0; ky < 3; ++ky) {
                        const int hy = yy + ky - 1;
                        if (hy < 0 || hy >= HO) continue;
                        #pragma unroll
                        for (int kx = 0; kx < 3; ++kx) {
                            const int hx = xx + kx - 1;
                            if (hx < 0 || hx >= WO) continue;
                            const float4* h4 = reinterpret_cast<const float4*>(
                                Hp + (size_t)(hy * WO + hx) * F);
                            float hv[F];
                            #pragma unroll
                            for (int j = 0; j < F / 4; ++j) {
                                float4 v4 = h4[j];
                                hv[4*j] = v4.x; hv[4*j+1] = v4.y;
                                hv[4*j+2] = v4.z; hv[4*j+3] = v4.w;
                            }
                            #pragma unroll
                            for (int ci = 0; ci < F; ++ci) {
                                const float v = hv[ci];
                                const float* wr =
                                    Wh + (size_t)((ky * 3 + kx) * F + ci) * G;
                                #pragma unroll
                                for (int g = 0; g < 4; ++g)
                                    #pragma unroll
                                    for (int f = 0; f < F; ++f)
                                        acc[g][f] = fmaf(v, wr[g * F + f], acc[g][f]);
                            }
                        }
                    }
                }

                // cell update fully in registers
                float ho[F];
                #pragma unroll
                for (int f = 0; f < F; ++f) {
                    const float ig = hsig(acc[0][f]), fg = hsig(acc[1][f]);
                    const float cc = ftanh(acc[2][f]), og = hsig(acc[3][f]);
                    creg[k][f] = fmaf(fg, creg[k][f], ig * cc);
                    ho[f] = og * ftanh(creg[k][f]);
                }
                float* hp = hcur + (size_t)pix * F;
                #pragma unroll
                for (int j = 0; j < F / 4; ++j)
                    reinterpret_cast<float4*>(hp)[j] = make_float4(
                        ho[4*j], ho[4*j+1], ho[4*j+2], ho[4*j+3]);
            }
        }
        grid.sync();
    }
    pool_phase<F, HO, WO, HP, WP>(ring + ((T - 1) & 1) * RS, pooled,
                                  T - 1, gtid, NTH);
}

// ---- gate-split cooperative layer kernel (L3, L4) ----
// Wave w owns gate w of 64 pixels (weights wave-uniform); LDS exchange; the
// (pixel,fo) item ownership in the epilogue is stable across t -> c in regs.
template<int CIN, int F, int HIN, int WIN>
__global__ __launch_bounds__(256, 2)
void layer_split_k(const float* __restrict__ P,
                   const float* __restrict__ Wx,
                   const float* __restrict__ Wh,
                   const float* __restrict__ bias,
                   float* __restrict__ ring,
                   float* __restrict__ pooled)
{
    constexpr int B = 32, T = 24, HO = HIN - 2, WO = WIN - 2, G = 4 * F;
    constexpr int HP = (HO + 1) / 2, WP = (WO + 1) / 2;
    constexpr int NPIX = B * HO * WO;
    constexpr size_t RS = (size_t)NPIX * F;
    constexpr int NIT = F / 4;                 // (64*F)/256 items per thread
    const int NTH  = gridDim.x * 256;
    const int gtid = blockIdx.x * 256 + threadIdx.x;
    const int tid  = threadIdx.x, lane = tid & 63;
    const int w    = __builtin_amdgcn_readfirstlane(tid >> 6);
    cg::grid_group grid = cg::this_grid();

    const int pix = blockIdx.x * 64 + lane;
    const int pp  = (pix < NPIX) ? pix : NPIX - 1;
    const int s   = pp % (HO * WO);
    const int b   = pp / (HO * WO);
    const int xx  = s % WO, yy = s / WO;

    __shared__ float gb[4][64 * F];
    float creg[NIT];
    #pragma unroll
    for (int r = 0; r < NIT; ++r) creg[r] = 0.0f;

    for (int t = 0; t < T; ++t) {
        if (t > 0)
            pool_phase<F, HO, WO, HP, WP>(ring + ((t - 1) & 1) * RS, pooled,
                                          t - 1, gtid, NTH);
        const float* hprev = ring + ((t + 1) & 1) * RS;
        float*       hcur  = ring + (t & 1) * RS;

        float acc[F];
        #pragma unroll
        for (int f = 0; f < F; ++f) acc[f] = bias[w * F + f];

        const float* Pt = P + (size_t)(b * T + t) * HIN * WIN * CIN;
        #pragma unroll
        for (int ky = 0; ky < 3; ++ky) {
            #pragma unroll
            for (int kx = 0; kx < 3; ++kx) {
                const float* prow = Pt + ((yy + ky) * WIN + (xx + kx)) * CIN;
                float pv[CIN];
                #pragma unroll
                for (int j = 0; j < CIN / 4; ++j) {
                    float4 v4 = reinterpret_cast<const float4*>(prow)[j];
                    pv[4*j] = v4.x; pv[4*j+1] = v4.y;
                    pv[4*j+2] = v4.z; pv[4*j+3] = v4.w;
                }
                #pragma unroll
                for (int ci = 0; ci < CIN; ++ci) {
                    const float v = pv[ci];
                    const float* wr =
                        Wx + (size_t)((ky * 3 + kx) * CIN + ci) * G + w * F;
                    #pragma unroll
                    for (int f = 0; f < F; ++f)
                        acc[f] = fmaf(v, wr[f], acc[f]);
                }
            }
        }

        if (t > 0) {
            const float* Hp = hprev + (size_t)b * HO * WO * F;
            #pragma unroll
            for (int ky = 0; ky < 3; ++ky) {
                const int hy = yy + ky - 1;
                if (hy < 0 || hy >= HO) continue;
                #pragma unroll
                for (int kx = 0; kx < 3; ++kx) {
                    const int hx = xx + kx - 1;
                    if (hx < 0 || hx >= WO) continue;
                    const float4* h4 = reinterpret_cast<const float4*>(
                        Hp + (size_t)(hy * WO + hx) * F);
                    float hv[F];
                    #pragma unroll
                    for (int j = 0; j < F / 4; ++j) {
                        float4 v4 = h4[j];
                        hv[4*j] = v4.x; hv[4*j+1] = v4.y;
                        hv[4*j+2] = v4.z; hv[4*j+3] = v4.w;
                    }
                    #pragma unroll
                    for (int ci = 0; ci < F; ++ci) {
                        const float v = hv[ci];
                        const float* wr =
                            Wh + (size_t)((ky * 3 + kx) * F + ci) * G + w * F;
                        #pragma unroll
                        for (int f = 0; f < F; ++f)
                            acc[f] = fmaf(v, wr[f], acc[f]);
                    }
                }
            }
        }

        #pragma unroll
        for (int f = 0; f < F; ++f) gb[w][lane * F + f] = acc[f];
        __syncthreads();

        #pragma unroll
        for (int r = 0; r < NIT; ++r) {
            const int it = r * 256 + tid;
            const int pl = it / F, fo = it % F;
            const int pix2 = blockIdx.x * 64 + pl;
            if (pix2 < NPIX) {
                const float ig = hsig(gb[0][it]), fg = hsig(gb[1][it]);
                const float cc = ftanh(gb[2][it]), og = hsig(gb[3][it]);
                creg[r] = fmaf(fg, creg[r], ig * cc);
                hcur[(size_t)pix2 * F + fo] = og * ftanh(creg[r]);
            }
        }
        grid.sync();   // also block-syncs: gb safe to rewrite next t
    }
    pool_phase<F, HO, WO, HP, WP>(ring + ((T - 1) & 1) * RS, pooled,
                                  T - 1, gtid, NTH);
}

// ---- Dense (18816 x 50) stage 1: partial sums over FLAT chunks ----
__global__ __launch_bounds__(256)
void dense_partial_k(const float* __restrict__ X, const float* __restrict__ Wd,
                     float* __restrict__ part)
{
    constexpr int FLAT = 18816, K = 50, NC = 12, CHUNK = FLAT / NC; // 1568
    const int b = blockIdx.x, ch = blockIdx.y;
    const int tid = threadIdx.x, lane = tid & 63, wv = tid >> 6;
    const float* x = X + (size_t)b * FLAT;
    const int i0 = ch * CHUNK + wv * (CHUNK / 4);
    float a0 = 0.f, a1 = 0.f, a2 = 0.f, a3 = 0.f;
    if (lane < K) {
        for (int i = i0; i < i0 + CHUNK / 4; i += 4) {
            a0 = fmaf(x[i + 0], Wd[(size_t)(i + 0) * K + lane], a0);
            a1 = fmaf(x[i + 1], Wd[(size_t)(i + 1) * K + lane], a1);
            a2 = fmaf(x[i + 2], Wd[(size_t)(i + 2) * K + lane], a2);
            a3 = fmaf(x[i + 3], Wd[(size_t)(i + 3) * K + lane], a3);
        }
    }
    __shared__ float red[256];
    red[tid] = (a0 + a1) + (a2 + a3);
    __syncthreads();
    if (tid < 64 && lane < K)
        part[((size_t)b * NC + ch) * K + lane]
            = red[tid] + red[tid + 64] + red[tid + 128] + red[tid + 192];
}

__global__ __launch_bounds__(64)
void dense_finish_k(const float* __restrict__ part, const float* __restrict__ bd,
                    float* __restrict__ out)
{
    constexpr int K = 50, NC = 12;
    const int b = blockIdx.x, lane = threadIdx.x;
    float v = -INFINITY;
    if (lane < K) {
        v = bd[lane];
        #pragma unroll
        for (int c = 0; c < NC; ++c)
            v += part[((size_t)b * NC + c) * K + lane];
    }
    float m = v;
    #pragma unroll
    for (int off = 32; off > 0; off >>= 1) m = fmaxf(m, __shfl_xor(m, off));
    float e = (lane < K) ? __expf(v - m) : 0.0f;
    float s = e;
    #pragma unroll
    for (int off = 32; off > 0; off >>= 1) s += __shfl_xor(s, off);
    if (lane < K) out[(size_t)b * K + lane] = e / s;
}

extern "C" void kernel_launch(void* const* d_in, const int* in_sizes, int n_in,
                              void* d_out, int out_size, void* d_ws, size_t ws_size,
                              hipStream_t stream)
{
    const float* x   = (const float*)d_in[0];
    const float* Wx1 = (const float*)d_in[1];
    const float* Wh1 = (const float*)d_in[2];
    const float* b1  = (const float*)d_in[3];
    const float* Wx2 = (const float*)d_in[4];
    const float* Wh2 = (const float*)d_in[5];
    const float* b2  = (const float*)d_in[6];
    const float* Wx3 = (const float*)d_in[7];
    const float* Wh3 = (const float*)d_in[8];
    const float* b3  = (const float*)d_in[9];
    const float* Wx4 = (const float*)d_in[10];
    const float* Wh4 = (const float*)d_in[11];
    const float* b4  = (const float*)d_in[12];
    const float* Wd  = (const float*)d_in[13];
    const float* bd  = (const float*)d_in[14];
    float* out = (float*)d_out;

    // ---- workspace (floats); total ~25M floats = 100 MB << ws_size ----
    float* ws    = (float*)d_ws;
    float* ring  = ws;                  // 2 * 2,032,128 (L1 max) = 4,064,256
    float* pool1 = ws + 4100096;        // 768*63*63*4  = 12,192,768
    float* pool2 = ws + 16292864;       // 768*31*31*8  =  5,904,384
    float* pool3 = ws + 22197248;       // 768*15*15*12 =  2,073,600
    float* pool4 = ws + 24270848;       // 768*7*7*16   =    602,112
    float* dpart = ws + 24872960;       // 32*12*50     =     19,200

    // L1: merged, 512 blocks (2/CU co-resident), 4 px/thread
    {
        const float* p = x; const float* wx = Wx1; const float* wh = Wh1;
        const float* bb = b1; float* rg = ring; float* po = pool1;
        void* args[] = {&p, &wx, &wh, &bb, &rg, &po};
        hipLaunchCooperativeKernel(
            (const void*)layer_merged_k<3, 4, 128, 128, 4>,
            dim3(512), dim3(256), args, 0, stream);
    }
    // L2: merged, 466 blocks, 1 px/thread
    {
        const float* p = pool1; const float* wx = Wx2; const float* wh = Wh2;
        const float* bb = b2; float* rg = ring; float* po = pool2;
        void* args[] = {&p, &wx, &wh, &bb, &rg, &po};
        hipLaunchCooperativeKernel(
            (const void*)layer_merged_k<4, 8, 63, 63, 1>,
            dim3(466), dim3(256), args, 0, stream);
    }
    // L3: gate-split, 421 blocks
    {
        const float* p = pool2; const float* wx = Wx3; const float* wh = Wh3;
        const float* bb = b3; float* rg = ring; float* po = pool3;
        void* args[] = {&p, &wx, &wh, &bb, &rg, &po};
        hipLaunchCooperativeKernel(
            (const void*)layer_split_k<8, 12, 31, 31>,
            dim3(421), dim3(256), args, 0, stream);
    }
    // L4: gate-split, 85 blocks
    {
        const float* p = pool3; const float* wx = Wx4; const float* wh = Wh4;
        const float* bb = b4; float* rg = ring; float* po = pool4;
        void* args[] = {&p, &wx, &wh, &bb, &rg, &po};
        hipLaunchCooperativeKernel(
            (const void*)layer_split_k<12, 16, 15, 15>,
            dim3(85), dim3(256), args, 0, stream);
    }

    // pool4 = (B, 18816) row-major == Keras Flatten
    dense_partial_k<<<dim3(32, 12), 256, 0, stream>>>(pool4, Wd, dpart);
    dense_finish_k<<<32, 64, 0, stream>>>(dpart, bd, out);
}

// Round 5
// 1762.820 us; speedup vs baseline: 3.5828x; 3.5828x over previous
//
#include <hip/hip_runtime.h>
#include <math.h>

// ---------------------------------------------------------------------------
// ConvLSTM stack: 4 x (ConvLSTM2D + MaxPool(1,2,2)) -> Flatten -> Dense -> Softmax
// Channels-last (B,T,H,W,C) contiguous everywhere (matches ref).
//
//  L1: Cin=3,  F=4,  128->126 -> pool 63   merged-gates, 1985 blocks/step
//  L2: Cin=4,  F=8,   63-> 61 -> pool 31   merged-gates,  466 blocks/step
//  L3: Cin=8,  F=12,  31-> 29 -> pool 15   gate-split waves, 421 blocks/step
//  L4: Cin=12, F=16,  15-> 13 -> pool 7    gate-split waves,  85 blocks/step
//
// Round-5: per-step launches (cooperative persistence regressed 3.5x in r4:
// grid.sync ~50us/XCD-wide sync + occupancy capped at 8 waves/CU). Input conv
// fused into every step (per-step P slice is 2-6 MB = cache-resident;
// recompute beats the 366 MB xg materialization that was write-bound in r3).
// Weights/bias are wave-uniform -> SGPR s_loads in all variants.
// ---------------------------------------------------------------------------

static __device__ __forceinline__ float hsig(float x) {
    return fminf(fmaxf(fmaf(0.2f, x, 0.5f), 0.0f), 1.0f);
}
static __device__ __forceinline__ float ftanh(float x) {
    // tanh(x) = 1 - 2/(e^{2x}+1);  |err| ~1e-6, exact at +-inf
    float e = __builtin_amdgcn_exp2f(x * 2.88539008177792681f);
    return 1.0f - 2.0f * __builtin_amdgcn_rcpf(e + 1.0f);
}

// ---- merged-gates step (L1, L2): thread = pixel, all 4 gates ----
template<int CIN, int F, int HIN, int WIN>
__global__ __launch_bounds__(256)
void step_merged_k(const float* __restrict__ P,    // (B,T,HIN,WIN,CIN)
                   const float* __restrict__ Wx,   // (3,3,CIN,4F)
                   const float* __restrict__ Wh,   // (3,3,F,4F)
                   const float* __restrict__ bias, // (4F)
                   float* __restrict__ hs,         // (B,T,HO,WO,F)
                   float* __restrict__ cbuf,       // (B,HO,WO,F)
                   int t)
{
    constexpr int B = 32, T = 24, HO = HIN - 2, WO = WIN - 2, G = 4 * F;
    constexpr int NPIX = B * HO * WO;
    const int pix = blockIdx.x * 256 + threadIdx.x;
    if (pix >= NPIX) return;
    const int s  = pix % (HO * WO);
    const int b  = pix / (HO * WO);
    const int xx = s % WO, yy = s / WO;

    float acc[4][F];
    #pragma unroll
    for (int g = 0; g < 4; ++g)
        #pragma unroll
        for (int f = 0; f < F; ++f) acc[g][f] = bias[g * F + f];   // s_load

    // ---- input conv (VALID): one contiguous row of 3*CIN floats per ky ----
    const float* Pt = P + (size_t)(b * T + t) * HIN * WIN * CIN;
    #pragma unroll
    for (int ky = 0; ky < 3; ++ky) {
        const float* prow = Pt + ((yy + ky) * WIN + xx) * CIN;
        float pv[3 * CIN];
        if constexpr (CIN % 4 == 0) {
            #pragma unroll
            for (int j = 0; j < 3 * CIN / 4; ++j) {
                float4 v4 = reinterpret_cast<const float4*>(prow)[j];
                pv[4*j] = v4.x; pv[4*j+1] = v4.y; pv[4*j+2] = v4.z; pv[4*j+3] = v4.w;
            }
        } else {
            #pragma unroll
            for (int j = 0; j < 3 * CIN; ++j) pv[j] = prow[j];  // contiguous run
        }
        #pragma unroll
        for (int kx = 0; kx < 3; ++kx)
            #pragma unroll
            for (int ci = 0; ci < CIN; ++ci) {
                const float v = pv[kx * CIN + ci];
                const float* wr = Wx + (size_t)((ky * 3 + kx) * CIN + ci) * G;
                #pragma unroll
                for (int g = 0; g < 4; ++g)
                    #pragma unroll
                    for (int f = 0; f < F; ++f)
                        acc[g][f] = fmaf(v, wr[g * F + f], acc[g][f]);
            }
    }

    // ---- recurrent conv (SAME, zero-pad) on h_{t-1} ----
    if (t > 0) {
        const float* Hp = hs + (size_t)(b * T + (t - 1)) * HO * WO * F;
        #pragma unroll
        for (int ky = 0; ky < 3; ++ky) {
            const int hy = yy + ky - 1;
            if (hy < 0 || hy >= HO) continue;
            #pragma unroll
            for (int kx = 0; kx < 3; ++kx) {
                const int hx = xx + kx - 1;
                if (hx < 0 || hx >= WO) continue;
                const float4* h4 = reinterpret_cast<const float4*>(
                    Hp + (size_t)(hy * WO + hx) * F);
                float hv[F];
                #pragma unroll
                for (int j = 0; j < F / 4; ++j) {
                    float4 v4 = h4[j];
                    hv[4*j] = v4.x; hv[4*j+1] = v4.y; hv[4*j+2] = v4.z; hv[4*j+3] = v4.w;
                }
                #pragma unroll
                for (int ci = 0; ci < F; ++ci) {
                    const float v = hv[ci];
                    const float* wr = Wh + (size_t)((ky * 3 + kx) * F + ci) * G;
                    #pragma unroll
                    for (int g = 0; g < 4; ++g)
                        #pragma unroll
                        for (int f = 0; f < F; ++f)
                            acc[g][f] = fmaf(v, wr[g * F + f], acc[g][f]);
                }
            }
        }
    }

    // ---- cell update (c round-trips via cbuf; L2-cache resident) ----
    float cn[F], ho[F];
    float* cp = cbuf + (size_t)pix * F;
    #pragma unroll
    for (int j = 0; j < F / 4; ++j) {
        float4 c4 = (t > 0) ? reinterpret_cast<float4*>(cp)[j]
                            : make_float4(0.f, 0.f, 0.f, 0.f);
        float cold[4] = {c4.x, c4.y, c4.z, c4.w};
        #pragma unroll
        for (int u = 0; u < 4; ++u) {
            const int f = 4 * j + u;
            const float ig = hsig(acc[0][f]), fg = hsig(acc[1][f]);
            const float cc = ftanh(acc[2][f]), og = hsig(acc[3][f]);
            cn[f] = fmaf(fg, cold[u], ig * cc);
            ho[f] = og * ftanh(cn[f]);
        }
        reinterpret_cast<float4*>(cp)[j] =
            make_float4(cn[4*j], cn[4*j+1], cn[4*j+2], cn[4*j+3]);
    }
    float* hp = hs + ((size_t)(b * T + t) * HO * WO + s) * F;
    #pragma unroll
    for (int j = 0; j < F / 4; ++j)
        reinterpret_cast<float4*>(hp)[j] =
            make_float4(ho[4*j], ho[4*j+1], ho[4*j+2], ho[4*j+3]);
}

// ---- gate-split step (L3, L4): wave w = gate w of 64 pixels ----
template<int CIN, int F, int HIN, int WIN>
__global__ __launch_bounds__(256)
void step_split_k(const float* __restrict__ P,
                  const float* __restrict__ Wx,
                  const float* __restrict__ Wh,
                  const float* __restrict__ bias,
                  float* __restrict__ hs,
                  float* __restrict__ cbuf,
                  int t)
{
    constexpr int B = 32, T = 24, HO = HIN - 2, WO = WIN - 2, G = 4 * F;
    constexpr int NPIX = B * HO * WO;
    const int tid = threadIdx.x, lane = tid & 63;
    const int w = __builtin_amdgcn_readfirstlane(tid >> 6);
    const int pix = blockIdx.x * 64 + lane;
    const int pp  = (pix < NPIX) ? pix : NPIX - 1;
    const int s   = pp % (HO * WO);
    const int b   = pp / (HO * WO);
    const int xx  = s % WO, yy = s / WO;

    float acc[F];
    #pragma unroll
    for (int f = 0; f < F; ++f) acc[f] = bias[w * F + f];

    const float* Pt = P + (size_t)(b * T + t) * HIN * WIN * CIN;
    #pragma unroll
    for (int ky = 0; ky < 3; ++ky) {
        #pragma unroll
        for (int kx = 0; kx < 3; ++kx) {
            const float* prow = Pt + ((yy + ky) * WIN + (xx + kx)) * CIN;
            float pv[CIN];
            #pragma unroll
            for (int j = 0; j < CIN / 4; ++j) {
                float4 v4 = reinterpret_cast<const float4*>(prow)[j];
                pv[4*j] = v4.x; pv[4*j+1] = v4.y; pv[4*j+2] = v4.z; pv[4*j+3] = v4.w;
            }
            #pragma unroll
            for (int ci = 0; ci < CIN; ++ci) {
                const float v = pv[ci];
                const float* wr = Wx + (size_t)((ky * 3 + kx) * CIN + ci) * G + w * F;
                #pragma unroll
                for (int f = 0; f < F; ++f)
                    acc[f] = fmaf(v, wr[f], acc[f]);
            }
        }
    }

    if (t > 0) {
        const float* Hp = hs + (size_t)(b * T + (t - 1)) * HO * WO * F;
        #pragma unroll
        for (int ky = 0; ky < 3; ++ky) {
            const int hy = yy + ky - 1;
            if (hy < 0 || hy >= HO) continue;
            #pragma unroll
            for (int kx = 0; kx < 3; ++kx) {
                const int hx = xx + kx - 1;
                if (hx < 0 || hx >= WO) continue;
                const float4* h4 = reinterpret_cast<const float4*>(
                    Hp + (size_t)(hy * WO + hx) * F);
                float hv[F];
                #pragma unroll
                for (int j = 0; j < F / 4; ++j) {
                    float4 v4 = h4[j];
                    hv[4*j] = v4.x; hv[4*j+1] = v4.y; hv[4*j+2] = v4.z; hv[4*j+3] = v4.w;
                }
                #pragma unroll
                for (int ci = 0; ci < F; ++ci) {
                    const float v = hv[ci];
                    const float* wr = Wh + (size_t)((ky * 3 + kx) * F + ci) * G + w * F;
                    #pragma unroll
                    for (int f = 0; f < F; ++f)
                        acc[f] = fmaf(v, wr[f], acc[f]);
                }
            }
        }
    }

    __shared__ float gb[4][64 * F];
    #pragma unroll
    for (int f = 0; f < F; ++f) gb[w][lane * F + f] = acc[f];
    __syncthreads();

    #pragma unroll
    for (int r = 0; r < F / 4; ++r) {          // 64*F items / 256 threads
        const int it = r * 256 + tid;
        const int pl = it / F, fo = it % F;
        const int pix2 = blockIdx.x * 64 + pl;
        if (pix2 < NPIX) {
            const float ig = hsig(gb[0][it]), fg = hsig(gb[1][it]);
            const float cc = ftanh(gb[2][it]), og = hsig(gb[3][it]);
            const size_t cix = (size_t)pix2 * F + fo;
            const float cold = (t > 0) ? cbuf[cix] : 0.0f;
            const float cnw = fmaf(fg, cold, ig * cc);
            cbuf[cix] = cnw;
            const int s2 = pix2 % (HO * WO);
            const int b2 = pix2 / (HO * WO);
            hs[((size_t)(b2 * T + t) * HO * WO + s2) * F + fo] = og * ftanh(cnw);
        }
    }
}

// MaxPool (1,2,2) stride (1,2,2) SAME over (N=B*T, H, W, C).
__global__ __launch_bounds__(256)
void pool_k(const float* __restrict__ in, float* __restrict__ out,
            int NT, int H, int W, int C, int HP, int WP)
{
    int idx = blockIdx.x * blockDim.x + threadIdx.x;
    int total = NT * HP * WP * C;
    if (idx >= total) return;
    int c  = idx % C;
    int xo = (idx / C) % WP;
    int yo = (idx / (C * WP)) % HP;
    int n  = idx / (C * WP * HP);
    int y0 = 2 * yo, x0 = 2 * xo;
    const float* base = in + (size_t)n * H * W * C + c;
    float m = base[(y0 * W + x0) * C];
    if (x0 + 1 < W) m = fmaxf(m, base[(y0 * W + x0 + 1) * C]);
    if (y0 + 1 < H) {
        m = fmaxf(m, base[((y0 + 1) * W + x0) * C]);
        if (x0 + 1 < W) m = fmaxf(m, base[((y0 + 1) * W + x0 + 1) * C]);
    }
    out[idx] = m;
}

// ---- Dense (18816 x 50) stage 1: partial sums over FLAT chunks ----
__global__ __launch_bounds__(256)
void dense_partial_k(const float* __restrict__ X, const float* __restrict__ Wd,
                     float* __restrict__ part)
{
    constexpr int FLAT = 18816, K = 50, NC = 12, CHUNK = FLAT / NC; // 1568
    const int b = blockIdx.x, ch = blockIdx.y;
    const int tid = threadIdx.x, lane = tid & 63, wv = tid >> 6;
    const float* x = X + (size_t)b * FLAT;
    const int i0 = ch * CHUNK + wv * (CHUNK / 4);
    float a0 = 0.f, a1 = 0.f, a2 = 0.f, a3 = 0.f;
    if (lane < K) {
        for (int i = i0; i < i0 + CHUNK / 4; i += 4) {
            a0 = fmaf(x[i + 0], Wd[(size_t)(i + 0) * K + lane], a0);
            a1 = fmaf(x[i + 1], Wd[(size_t)(i + 1) * K + lane], a1);
            a2 = fmaf(x[i + 2], Wd[(size_t)(i + 2) * K + lane], a2);
            a3 = fmaf(x[i + 3], Wd[(size_t)(i + 3) * K + lane], a3);
        }
    }
    __shared__ float red[256];
    red[tid] = (a0 + a1) + (a2 + a3);
    __syncthreads();
    if (tid < 64 && lane < K)
        part[((size_t)b * NC + ch) * K + lane]
            = red[tid] + red[tid + 64] + red[tid + 128] + red[tid + 192];
}

__global__ __launch_bounds__(64)
void dense_finish_k(const float* __restrict__ part, const float* __restrict__ bd,
                    float* __restrict__ out)
{
    constexpr int K = 50, NC = 12;
    const int b = blockIdx.x, lane = threadIdx.x;
    float v = -INFINITY;
    if (lane < K) {
        v = bd[lane];
        #pragma unroll
        for (int c = 0; c < NC; ++c)
            v += part[((size_t)b * NC + c) * K + lane];
    }
    float m = v;
    #pragma unroll
    for (int off = 32; off > 0; off >>= 1) m = fmaxf(m, __shfl_xor(m, off));
    float e = (lane < K) ? __expf(v - m) : 0.0f;
    float s = e;
    #pragma unroll
    for (int off = 32; off > 0; off >>= 1) s += __shfl_xor(s, off);
    if (lane < K) out[(size_t)b * K + lane] = e / s;
}

extern "C" void kernel_launch(void* const* d_in, const int* in_sizes, int n_in,
                              void* d_out, int out_size, void* d_ws, size_t ws_size,
                              hipStream_t stream)
{
    const float* x   = (const float*)d_in[0];
    const float* Wx1 = (const float*)d_in[1];
    const float* Wh1 = (const float*)d_in[2];
    const float* b1  = (const float*)d_in[3];
    const float* Wx2 = (const float*)d_in[4];
    const float* Wh2 = (const float*)d_in[5];
    const float* b2  = (const float*)d_in[6];
    const float* Wx3 = (const float*)d_in[7];
    const float* Wh3 = (const float*)d_in[8];
    const float* b3  = (const float*)d_in[9];
    const float* Wx4 = (const float*)d_in[10];
    const float* Wh4 = (const float*)d_in[11];
    const float* b4  = (const float*)d_in[12];
    const float* Wd  = (const float*)d_in[13];
    const float* bd  = (const float*)d_in[14];
    float* out = (float*)d_out;

    // ---- workspace (floats), sequential non-overlapping, ~286 MB ----
    float* ws    = (float*)d_ws;
    float* hs    = ws;                  // 768*126*126*4 = 48,771,072 (L1 max)
    float* pool1 = ws + 48771072;       // 768*63*63*4   = 12,192,768
    float* pool2 = ws + 60963840;       // 768*31*31*8   =  5,904,384
    float* pool3 = ws + 66868224;       // 768*15*15*12  =  2,073,600
    float* pool4 = ws + 68941824;       // 768*7*7*16    =    602,112
    float* cbuf  = ws + 69543936;       // 32*126*126*4  =  2,032,128 (L1 max)
    float* dpart = ws + 71576064;       // 32*12*50      =     19,200

    // L1: merged gates, 508,032 px
    for (int t = 0; t < 24; ++t)
        step_merged_k<3, 4, 128, 128><<<1985, 256, 0, stream>>>(
            x, Wx1, Wh1, b1, hs, cbuf, t);
    pool_k<<<47628, 256, 0, stream>>>(hs, pool1, 768, 126, 126, 4, 63, 63);

    // L2: merged gates, 119,072 px
    for (int t = 0; t < 24; ++t)
        step_merged_k<4, 8, 63, 63><<<466, 256, 0, stream>>>(
            pool1, Wx2, Wh2, b2, hs, cbuf, t);
    pool_k<<<23064, 256, 0, stream>>>(hs, pool2, 768, 61, 61, 8, 31, 31);

    // L3: gate-split, 26,912 px
    for (int t = 0; t < 24; ++t)
        step_split_k<8, 12, 31, 31><<<421, 256, 0, stream>>>(
            pool2, Wx3, Wh3, b3, hs, cbuf, t);
    pool_k<<<8100, 256, 0, stream>>>(hs, pool3, 768, 29, 29, 12, 15, 15);

    // L4: gate-split, 5,408 px
    for (int t = 0; t < 24; ++t)
        step_split_k<12, 16, 15, 15><<<85, 256, 0, stream>>>(
            pool3, Wx4, Wh4, b4, hs, cbuf, t);
    pool_k<<<2352, 256, 0, stream>>>(hs, pool4, 768, 13, 13, 16, 7, 7);

    // pool4 = (B, 18816) row-major == Keras Flatten
    dense_partial_k<<<dim3(32, 12), 256, 0, stream>>>(pool4, Wd, dpart);
    dense_finish_k<<<32, 64, 0, stream>>>(dpart, bd, out);
}

// Round 6
// 1566.619 us; speedup vs baseline: 4.0315x; 1.1252x over previous
//
#include <hip/hip_runtime.h>
#include <math.h>

// ---------------------------------------------------------------------------
// ConvLSTM stack: 4 x (ConvLSTM2D + MaxPool(1,2,2)) -> Flatten -> Dense -> Softmax
// Channels-last (B,T,H,W,C) contiguous everywhere (matches ref).
//
//  L1: Cin=3,  F=4,  128->126 -> pool 63   merged, 2px/thread, 993 blocks/step
//  L2: Cin=4,  F=8,   63-> 61 -> pool 31   gate-split 4 waves, 1861 blocks/step
//  L3: Cin=8,  F=12,  31-> 29 -> pool 15   split8 (gate x F-half), 421 blk x 512
//  L4: Cin=12, F=16,  15-> 13 -> pool 7    split8 (gate x F-half),  85 blk x 512
//
// Round-6: per-step launches (coop persistence regressed 3.5x in r4), input
// conv fused into every step (xg materialization was write-bound in r3).
// This round: L1 2px/thread (shared window, 2x ILP, -30% VMEM);
// L2 moved to gate-split (1.8 -> 7.3 waves/SIMD latency hiding);
// L3/L4 to 8-wave split (wave = gate x F-half) for 2x TLP in the
// parallelism-starved tail layers. Weights stay wave-uniform -> SGPR.
// ---------------------------------------------------------------------------

static __device__ __forceinline__ float hsig(float x) {
    return fminf(fmaxf(fmaf(0.2f, x, 0.5f), 0.0f), 1.0f);
}
static __device__ __forceinline__ float ftanh(float x) {
    // tanh(x) = 1 - 2/(e^{2x}+1);  |err| ~1e-6, exact at +-inf
    float e = __builtin_amdgcn_exp2f(x * 2.88539008177792681f);
    return 1.0f - 2.0f * __builtin_amdgcn_rcpf(e + 1.0f);
}

// ---- L1: merged gates, TWO adjacent pixels (same row) per thread ----
template<int CIN, int F, int HIN, int WIN>
__global__ __launch_bounds__(256)
void step_pair_k(const float* __restrict__ P,    // (B,T,HIN,WIN,CIN)
                 const float* __restrict__ Wx,   // (3,3,CIN,4F)
                 const float* __restrict__ Wh,   // (3,3,F,4F)
                 const float* __restrict__ bias, // (4F)
                 float* __restrict__ hs,         // (B,T,HO,WO,F)
                 float* __restrict__ cbuf,       // (B,HO,WO,F)
                 int t)
{
    constexpr int B = 32, T = 24, HO = HIN - 2, WO = WIN - 2, G = 4 * F;
    constexpr int XP = WO / 2;              // pixel-pairs per row (WO even)
    constexpr int NPAIR = B * HO * XP;
    const int id = blockIdx.x * 256 + threadIdx.x;
    if (id >= NPAIR) return;
    const int xp = id % XP;
    const int yy = (id / XP) % HO;
    const int b  = id / (XP * HO);
    const int x0 = 2 * xp;                  // left pixel column

    float acc[2][4][F];
    #pragma unroll
    for (int u = 0; u < 2; ++u)
        #pragma unroll
        for (int g = 0; g < 4; ++g)
            #pragma unroll
            for (int f = 0; f < F; ++f)
                acc[u][g][f] = bias[g * F + f];          // s_load

    // ---- input conv (VALID): shared 3x4 window, cols x0..x0+3 always valid
    const float* Pt = P + (size_t)(b * T + t) * HIN * WIN * CIN;
    #pragma unroll
    for (int ky = 0; ky < 3; ++ky) {
        const float* prow = Pt + ((size_t)(yy + ky) * WIN + x0) * CIN;
        float pv[4 * CIN];                  // 8B-aligned (x0 even)
        #pragma unroll
        for (int j = 0; j < 2 * CIN; ++j) {
            float2 v2 = reinterpret_cast<const float2*>(prow)[j];
            pv[2 * j] = v2.x; pv[2 * j + 1] = v2.y;
        }
        #pragma unroll
        for (int dx = 0; dx < 4; ++dx)
            #pragma unroll
            for (int ci = 0; ci < CIN; ++ci) {
                const float v = pv[dx * CIN + ci];
                #pragma unroll
                for (int u = 0; u < 2; ++u) {
                    const int kx = dx - u;
                    if (kx >= 0 && kx <= 2) {
                        const float* wr =
                            Wx + (size_t)((ky * 3 + kx) * CIN + ci) * G;
                        #pragma unroll
                        for (int g = 0; g < 4; ++g)
                            #pragma unroll
                            for (int f = 0; f < F; ++f)
                                acc[u][g][f] = fmaf(v, wr[g * F + f], acc[u][g][f]);
                    }
                }
            }
    }

    // ---- recurrent conv (SAME): shared 3x4 window, cols x0-1..x0+2 ----
    if (t > 0) {
        const float* Hp = hs + (size_t)(b * T + (t - 1)) * HO * WO * F;
        #pragma unroll
        for (int ky = 0; ky < 3; ++ky) {
            const int hy = yy + ky - 1;
            if (hy < 0 || hy >= HO) continue;
            const float* hrow = Hp + (size_t)hy * WO * F;
            #pragma unroll
            for (int dx = 0; dx < 4; ++dx) {
                const int hx = x0 - 1 + dx;
                if (dx == 0 && x0 == 0) continue;        // hx = -1
                if (dx == 3 && hx >= WO) continue;       // right edge
                const float4* h4 =
                    reinterpret_cast<const float4*>(hrow + (size_t)hx * F);
                float hv[F];
                #pragma unroll
                for (int j = 0; j < F / 4; ++j) {
                    float4 v4 = h4[j];
                    hv[4*j] = v4.x; hv[4*j+1] = v4.y;
                    hv[4*j+2] = v4.z; hv[4*j+3] = v4.w;
                }
                #pragma unroll
                for (int ci = 0; ci < F; ++ci) {
                    const float v = hv[ci];
                    #pragma unroll
                    for (int u = 0; u < 2; ++u) {
                        const int kx = dx - u;
                        if (kx >= 0 && kx <= 2) {
                            const float* wr =
                                Wh + (size_t)((ky * 3 + kx) * F + ci) * G;
                            #pragma unroll
                            for (int g = 0; g < 4; ++g)
                                #pragma unroll
                                for (int f = 0; f < F; ++f)
                                    acc[u][g][f] =
                                        fmaf(v, wr[g * F + f], acc[u][g][f]);
                        }
                    }
                }
            }
        }
    }

    // ---- cell update, both pixels ----
    #pragma unroll
    for (int u = 0; u < 2; ++u) {
        const size_t pix = ((size_t)b * HO + yy) * WO + (x0 + u);
        float cn[F], ho[F];
        float* cp = cbuf + pix * F;
        #pragma unroll
        for (int j = 0; j < F / 4; ++j) {
            float4 c4 = (t > 0) ? reinterpret_cast<float4*>(cp)[j]
                                : make_float4(0.f, 0.f, 0.f, 0.f);
            float cold[4] = {c4.x, c4.y, c4.z, c4.w};
            #pragma unroll
            for (int v = 0; v < 4; ++v) {
                const int f = 4 * j + v;
                const float ig = hsig(acc[u][0][f]), fg = hsig(acc[u][1][f]);
                const float cc = ftanh(acc[u][2][f]), og = hsig(acc[u][3][f]);
                cn[f] = fmaf(fg, cold[v], ig * cc);
                ho[f] = og * ftanh(cn[f]);
            }
            reinterpret_cast<float4*>(cp)[j] =
                make_float4(cn[4*j], cn[4*j+1], cn[4*j+2], cn[4*j+3]);
        }
        float* hp = hs + (size_t)(b * T + t) * HO * WO * F + pix % ((size_t)HO * WO * F);
        // (pix already includes b; recompute cleanly:)
        hp = hs + ((size_t)(b * T + t) * HO * WO + (size_t)yy * WO + (x0 + u)) * F;
        #pragma unroll
        for (int j = 0; j < F / 4; ++j)
            reinterpret_cast<float4*>(hp)[j] =
                make_float4(ho[4*j], ho[4*j+1], ho[4*j+2], ho[4*j+3]);
    }
}

// ---- gate-split step (L2): wave w = gate w of 64 pixels ----
template<int CIN, int F, int HIN, int WIN>
__global__ __launch_bounds__(256)
void step_split_k(const float* __restrict__ P,
                  const float* __restrict__ Wx,
                  const float* __restrict__ Wh,
                  const float* __restrict__ bias,
                  float* __restrict__ hs,
                  float* __restrict__ cbuf,
                  int t)
{
    constexpr int B = 32, T = 24, HO = HIN - 2, WO = WIN - 2, G = 4 * F;
    constexpr int NPIX = B * HO * WO;
    const int tid = threadIdx.x, lane = tid & 63;
    const int w = __builtin_amdgcn_readfirstlane(tid >> 6);
    const int pix = blockIdx.x * 64 + lane;
    const int pp  = (pix < NPIX) ? pix : NPIX - 1;
    const int s   = pp % (HO * WO);
    const int b   = pp / (HO * WO);
    const int xx  = s % WO, yy = s / WO;

    float acc[F];
    #pragma unroll
    for (int f = 0; f < F; ++f) acc[f] = bias[w * F + f];

    const float* Pt = P + (size_t)(b * T + t) * HIN * WIN * CIN;
    #pragma unroll
    for (int ky = 0; ky < 3; ++ky) {
        #pragma unroll
        for (int kx = 0; kx < 3; ++kx) {
            const float* prow = Pt + ((size_t)(yy + ky) * WIN + (xx + kx)) * CIN;
            float pv[CIN];
            #pragma unroll
            for (int j = 0; j < CIN / 4; ++j) {
                float4 v4 = reinterpret_cast<const float4*>(prow)[j];
                pv[4*j] = v4.x; pv[4*j+1] = v4.y; pv[4*j+2] = v4.z; pv[4*j+3] = v4.w;
            }
            #pragma unroll
            for (int ci = 0; ci < CIN; ++ci) {
                const float v = pv[ci];
                const float* wr = Wx + (size_t)((ky * 3 + kx) * CIN + ci) * G + w * F;
                #pragma unroll
                for (int f = 0; f < F; ++f)
                    acc[f] = fmaf(v, wr[f], acc[f]);
            }
        }
    }

    if (t > 0) {
        const float* Hp = hs + (size_t)(b * T + (t - 1)) * HO * WO * F;
        #pragma unroll
        for (int ky = 0; ky < 3; ++ky) {
            const int hy = yy + ky - 1;
            if (hy < 0 || hy >= HO) continue;
            #pragma unroll
            for (int kx = 0; kx < 3; ++kx) {
                const int hx = xx + kx - 1;
                if (hx < 0 || hx >= WO) continue;
                const float4* h4 = reinterpret_cast<const float4*>(
                    Hp + ((size_t)hy * WO + hx) * F);
                float hv[F];
                #pragma unroll
                for (int j = 0; j < F / 4; ++j) {
                    float4 v4 = h4[j];
                    hv[4*j] = v4.x; hv[4*j+1] = v4.y; hv[4*j+2] = v4.z; hv[4*j+3] = v4.w;
                }
                #pragma unroll
                for (int ci = 0; ci < F; ++ci) {
                    const float v = hv[ci];
                    const float* wr = Wh + (size_t)((ky * 3 + kx) * F + ci) * G + w * F;
                    #pragma unroll
                    for (int f = 0; f < F; ++f)
                        acc[f] = fmaf(v, wr[f], acc[f]);
                }
            }
        }
    }

    __shared__ float gb[4][64 * F];
    #pragma unroll
    for (int f = 0; f < F; ++f) gb[w][lane * F + f] = acc[f];
    __syncthreads();

    #pragma unroll
    for (int r = 0; r < F / 4; ++r) {          // 64*F items / 256 threads
        const int it = r * 256 + tid;
        const int pl = it / F, fo = it % F;
        const int pix2 = blockIdx.x * 64 + pl;
        if (pix2 < NPIX) {
            const float ig = hsig(gb[0][it]), fg = hsig(gb[1][it]);
            const float cc = ftanh(gb[2][it]), og = hsig(gb[3][it]);
            const size_t cix = (size_t)pix2 * F + fo;
            const float cold = (t > 0) ? cbuf[cix] : 0.0f;
            const float cnw = fmaf(fg, cold, ig * cc);
            cbuf[cix] = cnw;
            const int s2 = pix2 % (HO * WO);
            const int b2 = pix2 / (HO * WO);
            hs[((size_t)(b2 * T + t) * HO * WO + s2) * F + fo] = og * ftanh(cnw);
        }
    }
}

// ---- 8-wave split step (L3, L4): wave = (gate, F-half), 512 threads ----
template<int CIN, int F, int HIN, int WIN>
__global__ __launch_bounds__(512)
void step_split8_k(const float* __restrict__ P,
                   const float* __restrict__ Wx,
                   const float* __restrict__ Wh,
                   const float* __restrict__ bias,
                   float* __restrict__ hs,
                   float* __restrict__ cbuf,
                   int t)
{
    constexpr int B = 32, T = 24, HO = HIN - 2, WO = WIN - 2, G = 4 * F;
    constexpr int NPIX = B * HO * WO;
    constexpr int FH = F / 2;
    const int tid = threadIdx.x, lane = tid & 63;
    const int wv = __builtin_amdgcn_readfirstlane(tid >> 6);  // 0..7
    const int g  = wv & 3;            // gate
    const int hf = wv >> 2;           // F-half
    const int pix = blockIdx.x * 64 + lane;
    const int pp  = (pix < NPIX) ? pix : NPIX - 1;
    const int s   = pp % (HO * WO);
    const int b   = pp / (HO * WO);
    const int xx  = s % WO, yy = s / WO;

    float acc[FH];
    #pragma unroll
    for (int f = 0; f < FH; ++f) acc[f] = bias[g * F + hf * FH + f];

    const float* Pt = P + (size_t)(b * T + t) * HIN * WIN * CIN;
    #pragma unroll
    for (int ky = 0; ky < 3; ++ky) {
        #pragma unroll
        for (int kx = 0; kx < 3; ++kx) {
            const float* prow = Pt + ((size_t)(yy + ky) * WIN + (xx + kx)) * CIN;
            float pv[CIN];
            #pragma unroll
            for (int j = 0; j < CIN / 4; ++j) {
                float4 v4 = reinterpret_cast<const float4*>(prow)[j];
                pv[4*j] = v4.x; pv[4*j+1] = v4.y; pv[4*j+2] = v4.z; pv[4*j+3] = v4.w;
            }
            #pragma unroll
            for (int ci = 0; ci < CIN; ++ci) {
                const float v = pv[ci];
                const float* wr =
                    Wx + (size_t)((ky * 3 + kx) * CIN + ci) * G + g * F + hf * FH;
                #pragma unroll
                for (int f = 0; f < FH; ++f)
                    acc[f] = fmaf(v, wr[f], acc[f]);
            }
        }
    }

    if (t > 0) {
        const float* Hp = hs + (size_t)(b * T + (t - 1)) * HO * WO * F;
        #pragma unroll
        for (int ky = 0; ky < 3; ++ky) {
            const int hy = yy + ky - 1;
            if (hy < 0 || hy >= HO) continue;
            #pragma unroll
            for (int kx = 0; kx < 3; ++kx) {
                const int hx = xx + kx - 1;
                if (hx < 0 || hx >= WO) continue;
                const float4* h4 = reinterpret_cast<const float4*>(
                    Hp + ((size_t)hy * WO + hx) * F);
                float hv[F];
                #pragma unroll
                for (int j = 0; j < F / 4; ++j) {
                    float4 v4 = h4[j];
                    hv[4*j] = v4.x; hv[4*j+1] = v4.y; hv[4*j+2] = v4.z; hv[4*j+3] = v4.w;
                }
                #pragma unroll
                for (int ci = 0; ci < F; ++ci) {
                    const float v = hv[ci];
                    const float* wr =
                        Wh + (size_t)((ky * 3 + kx) * F + ci) * G + g * F + hf * FH;
                    #pragma unroll
                    for (int f = 0; f < FH; ++f)
                        acc[f] = fmaf(v, wr[f], acc[f]);
                }
            }
        }
    }

    __shared__ float gb[4][64 * F];
    #pragma unroll
    for (int f = 0; f < FH; ++f) gb[g][lane * F + hf * FH + f] = acc[f];
    __syncthreads();

    constexpr int NITEM = 64 * F;
    #pragma unroll
    for (int r = 0; r < (NITEM + 511) / 512; ++r) {
        const int it = r * 512 + tid;
        if (it < NITEM) {
            const int pl = it / F, fo = it % F;
            const int pix2 = blockIdx.x * 64 + pl;
            if (pix2 < NPIX) {
                const float ig = hsig(gb[0][it]), fg = hsig(gb[1][it]);
                const float cc = ftanh(gb[2][it]), og = hsig(gb[3][it]);
                const size_t cix = (size_t)pix2 * F + fo;
                const float cold = (t > 0) ? cbuf[cix] : 0.0f;
                const float cnw = fmaf(fg, cold, ig * cc);
                cbuf[cix] = cnw;
                const int s2 = pix2 % (HO * WO);
                const int b2 = pix2 / (HO * WO);
                hs[((size_t)(b2 * T + t) * HO * WO + s2) * F + fo] = og * ftanh(cnw);
            }
        }
    }
}

// MaxPool (1,2,2) stride (1,2,2) SAME over (N=B*T, H, W, C).
__global__ __launch_bounds__(256)
void pool_k(const float* __restrict__ in, float* __restrict__ out,
            int NT, int H, int W, int C, int HP, int WP)
{
    int idx = blockIdx.x * blockDim.x + threadIdx.x;
    int total = NT * HP * WP * C;
    if (idx >= total) return;
    int c  = idx % C;
    int xo = (idx / C) % WP;
    int yo = (idx / (C * WP)) % HP;
    int n  = idx / (C * WP * HP);
    int y0 = 2 * yo, x0 = 2 * xo;
    const float* base = in + (size_t)n * H * W * C + c;
    float m = base[(y0 * W + x0) * C];
    if (x0 + 1 < W) m = fmaxf(m, base[(y0 * W + x0 + 1) * C]);
    if (y0 + 1 < H) {
        m = fmaxf(m, base[((y0 + 1) * W + x0) * C]);
        if (x0 + 1 < W) m = fmaxf(m, base[((y0 + 1) * W + x0 + 1) * C]);
    }
    out[idx] = m;
}

// ---- Dense (18816 x 50) stage 1: partial sums over FLAT chunks ----
__global__ __launch_bounds__(256)
void dense_partial_k(const float* __restrict__ X, const float* __restrict__ Wd,
                     float* __restrict__ part)
{
    constexpr int FLAT = 18816, K = 50, NC = 12, CHUNK = FLAT / NC; // 1568
    const int b = blockIdx.x, ch = blockIdx.y;
    const int tid = threadIdx.x, lane = tid & 63, wv = tid >> 6;
    const float* x = X + (size_t)b * FLAT;
    const int i0 = ch * CHUNK + wv * (CHUNK / 4);
    float a0 = 0.f, a1 = 0.f, a2 = 0.f, a3 = 0.f;
    if (lane < K) {
        for (int i = i0; i < i0 + CHUNK / 4; i += 4) {
            a0 = fmaf(x[i + 0], Wd[(size_t)(i + 0) * K + lane], a0);
            a1 = fmaf(x[i + 1], Wd[(size_t)(i + 1) * K + lane], a1);
            a2 = fmaf(x[i + 2], Wd[(size_t)(i + 2) * K + lane], a2);
            a3 = fmaf(x[i + 3], Wd[(size_t)(i + 3) * K + lane], a3);
        }
    }
    __shared__ float red[256];
    red[tid] = (a0 + a1) + (a2 + a3);
    __syncthreads();
    if (tid < 64 && lane < K)
        part[((size_t)b * NC + ch) * K + lane]
            = red[tid] + red[tid + 64] + red[tid + 128] + red[tid + 192];
}

__global__ __launch_bounds__(64)
void dense_finish_k(const float* __restrict__ part, const float* __restrict__ bd,
                    float* __restrict__ out)
{
    constexpr int K = 50, NC = 12;
    const int b = blockIdx.x, lane = threadIdx.x;
    float v = -INFINITY;
    if (lane < K) {
        v = bd[lane];
        #pragma unroll
        for (int c = 0; c < NC; ++c)
            v += part[((size_t)b * NC + c) * K + lane];
    }
    float m = v;
    #pragma unroll
    for (int off = 32; off > 0; off >>= 1) m = fmaxf(m, __shfl_xor(m, off));
    float e = (lane < K) ? __expf(v - m) : 0.0f;
    float s = e;
    #pragma unroll
    for (int off = 32; off > 0; off >>= 1) s += __shfl_xor(s, off);
    if (lane < K) out[(size_t)b * K + lane] = e / s;
}

extern "C" void kernel_launch(void* const* d_in, const int* in_sizes, int n_in,
                              void* d_out, int out_size, void* d_ws, size_t ws_size,
                              hipStream_t stream)
{
    const float* x   = (const float*)d_in[0];
    const float* Wx1 = (const float*)d_in[1];
    const float* Wh1 = (const float*)d_in[2];
    const float* b1  = (const float*)d_in[3];
    const float* Wx2 = (const float*)d_in[4];
    const float* Wh2 = (const float*)d_in[5];
    const float* b2  = (const float*)d_in[6];
    const float* Wx3 = (const float*)d_in[7];
    const float* Wh3 = (const float*)d_in[8];
    const float* b3  = (const float*)d_in[9];
    const float* Wx4 = (const float*)d_in[10];
    const float* Wh4 = (const float*)d_in[11];
    const float* b4  = (const float*)d_in[12];
    const float* Wd  = (const float*)d_in[13];
    const float* bd  = (const float*)d_in[14];
    float* out = (float*)d_out;

    // ---- workspace (floats), sequential non-overlapping, ~286 MB ----
    float* ws    = (float*)d_ws;
    float* hs    = ws;                  // 768*126*126*4 = 48,771,072 (L1 max)
    float* pool1 = ws + 48771072;       // 768*63*63*4   = 12,192,768
    float* pool2 = ws + 60963840;       // 768*31*31*8   =  5,904,384
    float* pool3 = ws + 66868224;       // 768*15*15*12  =  2,073,600
    float* pool4 = ws + 68941824;       // 768*7*7*16    =    602,112
    float* cbuf  = ws + 69543936;       // 32*126*126*4  =  2,032,128 (L1 max)
    float* dpart = ws + 71576064;       // 32*12*50      =     19,200

    // L1: merged gates, 2 px/thread, 254,016 pairs
    for (int t = 0; t < 24; ++t)
        step_pair_k<3, 4, 128, 128><<<993, 256, 0, stream>>>(
            x, Wx1, Wh1, b1, hs, cbuf, t);
    pool_k<<<47628, 256, 0, stream>>>(hs, pool1, 768, 126, 126, 4, 63, 63);

    // L2: gate-split, 119,072 px -> 1861 blocks, 7.3 waves/SIMD
    for (int t = 0; t < 24; ++t)
        step_split_k<4, 8, 63, 63><<<1861, 256, 0, stream>>>(
            pool1, Wx2, Wh2, b2, hs, cbuf, t);
    pool_k<<<23064, 256, 0, stream>>>(hs, pool2, 768, 61, 61, 8, 31, 31);

    // L3: 8-wave split, 26,912 px -> 421 blocks x 512
    for (int t = 0; t < 24; ++t)
        step_split8_k<8, 12, 31, 31><<<421, 512, 0, stream>>>(
            pool2, Wx3, Wh3, b3, hs, cbuf, t);
    pool_k<<<8100, 256, 0, stream>>>(hs, pool3, 768, 29, 29, 12, 15, 15);

    // L4: 8-wave split, 5,408 px -> 85 blocks x 512
    for (int t = 0; t < 24; ++t)
        step_split8_k<12, 16, 15, 15><<<85, 512, 0, stream>>>(
            pool3, Wx4, Wh4, b4, hs, cbuf, t);
    pool_k<<<2352, 256, 0, stream>>>(hs, pool4, 768, 13, 13, 16, 7, 7);

    // pool4 = (B, 18816) row-major == Keras Flatten
    dense_partial_k<<<dim3(32, 12), 256, 0, stream>>>(pool4, Wd, dpart);
    dense_finish_k<<<32, 64, 0, stream>>>(dpart, bd, out);
}